// Round 1
// baseline (392.744 us; speedup 1.0000x reference)
//
#include <hip/hip_runtime.h>

#define B_ 16
#define N_ 576
#define C_ 768
#define H_ 12
#define HD_ 64
#define M_ (B_*N_)      // 9216
#define C3_ (3*C_)      // 2304

typedef _Float16 f16;
typedef _Float16 f16x8 __attribute__((ext_vector_type(8)));
typedef _Float16 f16x4 __attribute__((ext_vector_type(4)));
typedef float f32x4 __attribute__((ext_vector_type(4)));

// ---------------- convert fp32 -> fp16 (vectorized x4) ----------------
__global__ void cvt_f32_f16(const float* __restrict__ in, f16* __restrict__ out, int n4) {
    int i = blockIdx.x * blockDim.x + threadIdx.x;
    int stride = gridDim.x * blockDim.x;
    for (; i < n4; i += stride) {
        float4 v = ((const float4*)in)[i];
        f16x4 o = { (f16)v.x, (f16)v.y, (f16)v.z, (f16)v.w };
        ((f16x4*)out)[i] = o;
    }
}

// LDS XOR swizzle: row stride 32 halfs (64B). Spread the four 16B slots per
// row across banks: slot' = slot ^ ((row>>1)&3) -> 2-way max (free).
__device__ __forceinline__ int swz(int row, int slot) {
    return row * 32 + ((slot ^ ((row >> 1) & 3)) * 8);
}

// ---------------- QKV GEMM: [9216x768] @ [2304x768]^T, scatter epilogue ----------------
__global__ __launch_bounds__(256) void gemm_qkv(const f16* __restrict__ A, const f16* __restrict__ Bw,
                                                f16* __restrict__ Qo, f16* __restrict__ Ko, f16* __restrict__ Vo) {
    __shared__ __align__(16) f16 lA[128 * 32];
    __shared__ __align__(16) f16 lB[128 * 32];
    const int K = C_;
    int m0 = blockIdx.x * 128, n0 = blockIdx.y * 128;
    int t = threadIdx.x, lane = t & 63, wave = t >> 6;
    int wm = (wave >> 1) * 64, wn = (wave & 1) * 64;
    int srow = t >> 2, sslot = t & 3, scol = sslot * 8;
    f32x4 acc[4][4] = {};
    for (int k0 = 0; k0 < K; k0 += 32) {
        *(f16x8*)(lA + swz(srow,      sslot)) = *(const f16x8*)(A + (size_t)(m0 + srow)      * K + k0 + scol);
        *(f16x8*)(lA + swz(srow + 64, sslot)) = *(const f16x8*)(A + (size_t)(m0 + srow + 64) * K + k0 + scol);
        *(f16x8*)(lB + swz(srow,      sslot)) = *(const f16x8*)(Bw + (size_t)(n0 + srow)      * K + k0 + scol);
        *(f16x8*)(lB + swz(srow + 64, sslot)) = *(const f16x8*)(Bw + (size_t)(n0 + srow + 64) * K + k0 + scol);
        __syncthreads();
        f16x8 af[4], bf[4];
#pragma unroll
        for (int i = 0; i < 4; ++i) {
            af[i] = *(const f16x8*)(lA + swz(wm + i * 16 + (lane & 15), lane >> 4));
            bf[i] = *(const f16x8*)(lB + swz(wn + i * 16 + (lane & 15), lane >> 4));
        }
#pragma unroll
        for (int i = 0; i < 4; ++i)
#pragma unroll
            for (int j = 0; j < 4; ++j)
                acc[i][j] = __builtin_amdgcn_mfma_f32_16x16x32_f16(af[i], bf[j], acc[i][j], 0, 0, 0);
        __syncthreads();
    }
#pragma unroll
    for (int i = 0; i < 4; ++i) {
        int row0 = m0 + wm + i * 16 + ((lane >> 4) * 4);
#pragma unroll
        for (int j = 0; j < 4; ++j) {
            int col = n0 + wn + j * 16 + (lane & 15);
            int tsel = col / C_;
            int rem = col - tsel * C_;
            int h = rem >> 6, d = rem & 63;
#pragma unroll
            for (int r = 0; r < 4; ++r) {
                int rr = row0 + r;
                int bb = rr / N_, nn = rr - bb * N_;
                size_t o = (((size_t)bb * H_ + h) * N_ + nn) * HD_ + d;
                float v = acc[i][j][r];
                if (tsel == 0)      Qo[o] = (f16)(v * 0.125f);   // fold SCALE into Q
                else if (tsel == 1) Ko[o] = (f16)v;
                else                Vo[o] = (f16)v;
            }
        }
    }
}

// ---------------- proj GEMM: [9216x768] @ [768x768]^T + bias -> fp32 out ----------------
__global__ __launch_bounds__(256) void gemm_proj(const f16* __restrict__ A, const f16* __restrict__ Bw,
                                                 const float* __restrict__ bias, float* __restrict__ out) {
    __shared__ __align__(16) f16 lA[128 * 32];
    __shared__ __align__(16) f16 lB[128 * 32];
    const int K = C_;
    int m0 = blockIdx.x * 128, n0 = blockIdx.y * 128;
    int t = threadIdx.x, lane = t & 63, wave = t >> 6;
    int wm = (wave >> 1) * 64, wn = (wave & 1) * 64;
    int srow = t >> 2, sslot = t & 3, scol = sslot * 8;
    f32x4 acc[4][4] = {};
    for (int k0 = 0; k0 < K; k0 += 32) {
        *(f16x8*)(lA + swz(srow,      sslot)) = *(const f16x8*)(A + (size_t)(m0 + srow)      * K + k0 + scol);
        *(f16x8*)(lA + swz(srow + 64, sslot)) = *(const f16x8*)(A + (size_t)(m0 + srow + 64) * K + k0 + scol);
        *(f16x8*)(lB + swz(srow,      sslot)) = *(const f16x8*)(Bw + (size_t)(n0 + srow)      * K + k0 + scol);
        *(f16x8*)(lB + swz(srow + 64, sslot)) = *(const f16x8*)(Bw + (size_t)(n0 + srow + 64) * K + k0 + scol);
        __syncthreads();
        f16x8 af[4], bf[4];
#pragma unroll
        for (int i = 0; i < 4; ++i) {
            af[i] = *(const f16x8*)(lA + swz(wm + i * 16 + (lane & 15), lane >> 4));
            bf[i] = *(const f16x8*)(lB + swz(wn + i * 16 + (lane & 15), lane >> 4));
        }
#pragma unroll
        for (int i = 0; i < 4; ++i)
#pragma unroll
            for (int j = 0; j < 4; ++j)
                acc[i][j] = __builtin_amdgcn_mfma_f32_16x16x32_f16(af[i], bf[j], acc[i][j], 0, 0, 0);
        __syncthreads();
    }
#pragma unroll
    for (int i = 0; i < 4; ++i) {
        int row0 = m0 + wm + i * 16 + ((lane >> 4) * 4);
#pragma unroll
        for (int j = 0; j < 4; ++j) {
            int col = n0 + wn + j * 16 + (lane & 15);
            float bv = bias[col];
#pragma unroll
            for (int r = 0; r < 4; ++r)
                out[(size_t)(row0 + r) * C_ + col] = acc[i][j][r] + bv;
        }
    }
}

// ---------------- V transpose: [b][h][n][64] -> [b][h][64][n] ----------------
__global__ void transpose_v(const f16* __restrict__ V, f16* __restrict__ VT) {
    __shared__ f16 tile[64][68];
    int bh = blockIdx.y, n0 = blockIdx.x * 64;
    const f16* src = V + (size_t)bh * N_ * HD_;
    f16* dst = VT + (size_t)bh * HD_ * N_;
    int t = threadIdx.x;
#pragma unroll
    for (int i = 0; i < 16; ++i) {
        int e = i * 256 + t;
        int r = e >> 6, c = e & 63;
        tile[r][c] = src[(size_t)(n0 + r) * HD_ + c];
    }
    __syncthreads();
#pragma unroll
    for (int i = 0; i < 16; ++i) {
        int e = i * 256 + t;
        int d = e >> 6, nl = e & 63;
        dst[(size_t)d * N_ + n0 + nl] = tile[nl][d];
    }
}

// ---------------- scores + pre-softmax head mix: S'[b,g,m,n] ----------------
// grid (18 mtiles, 18 ntiles, 16 b); each wave computes one 16x16 (m,n) quadrant, all 12 heads
__global__ __launch_bounds__(256) void scores_mix(const f16* __restrict__ Qh, const f16* __restrict__ Kh,
                                                  const float* __restrict__ Wl, const float* __restrict__ bl,
                                                  f16* __restrict__ Sp) {
    int b = blockIdx.z;
    int t = threadIdx.x, lane = t & 63, wave = t >> 6;
    int m0 = blockIdx.x * 32 + (wave >> 1) * 16;
    int n0 = blockIdx.y * 32 + (wave & 1) * 16;
    f32x4 s[H_];
#pragma unroll
    for (int h = 0; h < H_; ++h) {
        const f16* qb = Qh + (((size_t)b * H_ + h) * N_ + m0 + (lane & 15)) * HD_ + (lane >> 4) * 8;
        const f16* kb = Kh + (((size_t)b * H_ + h) * N_ + n0 + (lane & 15)) * HD_ + (lane >> 4) * 8;
        f16x8 q0 = *(const f16x8*)qb;
        f16x8 q1 = *(const f16x8*)(qb + 32);
        f16x8 k0 = *(const f16x8*)kb;
        f16x8 k1 = *(const f16x8*)(kb + 32);
        f32x4 a = {0.f, 0.f, 0.f, 0.f};
        a = __builtin_amdgcn_mfma_f32_16x16x32_f16(q0, k0, a, 0, 0, 0);
        a = __builtin_amdgcn_mfma_f32_16x16x32_f16(q1, k1, a, 0, 0, 0);
        s[h] = a;
    }
    int col = n0 + (lane & 15);
    int row0 = m0 + (lane >> 4) * 4;
#pragma unroll
    for (int g = 0; g < H_; ++g) {
        float bg = bl[g];
        f32x4 w = {bg, bg, bg, bg};
#pragma unroll
        for (int h = 0; h < H_; ++h) {
            float wl = Wl[g * H_ + h];
            w += wl * s[h];
        }
        size_t base = ((size_t)b * H_ + g) * N_;
#pragma unroll
        for (int r = 0; r < 4; ++r)
            Sp[(base + row0 + r) * N_ + col] = (f16)w[r];
    }
}

// ---------------- per-row max & sumexp over n (rows = b*H*N) ----------------
__global__ __launch_bounds__(256) void row_stats(const f16* __restrict__ Sp, float* __restrict__ rmax,
                                                 float* __restrict__ rsum) {
    int row = blockIdx.x * 4 + (threadIdx.x >> 6);
    int lane = threadIdx.x & 63;
    const f16* p = Sp + (size_t)row * N_;
    float v[9];
    float mx = -1e30f;
#pragma unroll
    for (int i = 0; i < 9; ++i) { v[i] = (float)p[i * 64 + lane]; mx = fmaxf(mx, v[i]); }
#pragma unroll
    for (int o = 32; o > 0; o >>= 1) mx = fmaxf(mx, __shfl_xor(mx, o, 64));
    float s = 0.f;
#pragma unroll
    for (int i = 0; i < 9; ++i) s += __expf(v[i] - mx);
#pragma unroll
    for (int o = 32; o > 0; o >>= 1) s += __shfl_xor(s, o, 64);
    if (lane == 0) { rmax[row] = mx; rsum[row] = s; }
}

// ---------------- softmax apply + post-softmax head mix (in-place on Sp) ----------------
__global__ __launch_bounds__(256) void apply_mix(f16* __restrict__ Sp, const float* __restrict__ rmax,
                                                 const float* __restrict__ rsum, const float* __restrict__ Ww,
                                                 const float* __restrict__ bw) {
    int m = blockIdx.x;   // 576
    int b = blockIdx.y;   // 16
    float mh[H_], il[H_];
#pragma unroll
    for (int h = 0; h < H_; ++h) {
        int sr = (b * H_ + h) * N_ + m;
        mh[h] = rmax[sr];
        il[h] = 1.f / rsum[sr];
    }
    size_t base = ((size_t)b * H_) * N_ * N_ + (size_t)m * N_;
    const size_t hs = (size_t)N_ * N_;
    for (int n = threadIdx.x; n < N_; n += 256) {
        float p[H_];
#pragma unroll
        for (int h = 0; h < H_; ++h)
            p[h] = __expf((float)Sp[base + hs * h + n] - mh[h]) * il[h];
#pragma unroll
        for (int g = 0; g < H_; ++g) {
            float w = bw[g];
#pragma unroll
            for (int h = 0; h < H_; ++h) w += Ww[g * H_ + h] * p[h];
            Sp[base + hs * g + n] = (f16)w;
        }
    }
}

// ---------------- PV: O[b,g,m,d] = sum_n A'[b,g,m,n] * V[b,g,n,d] ----------------
// grid (9 mtiles, 192 bg); each wave: 16 m rows x all 64 d
__global__ __launch_bounds__(256) void pv(const f16* __restrict__ Sp, const f16* __restrict__ VT,
                                          f16* __restrict__ Oh) {
    int bg = blockIdx.y;
    int t = threadIdx.x, lane = t & 63, wave = t >> 6;
    int m0 = blockIdx.x * 64 + wave * 16;
    const f16* Ab = Sp + ((size_t)bg * N_ + m0 + (lane & 15)) * N_ + (lane >> 4) * 8;
    const f16* Vb = VT + (size_t)bg * HD_ * N_ + (size_t)(lane & 15) * N_ + (lane >> 4) * 8;
    f32x4 acc[4] = {};
    for (int k = 0; k < N_; k += 32) {
        f16x8 a = *(const f16x8*)(Ab + k);
#pragma unroll
        for (int dt = 0; dt < 4; ++dt) {
            f16x8 bb = *(const f16x8*)(Vb + (size_t)dt * 16 * N_ + k);
            acc[dt] = __builtin_amdgcn_mfma_f32_16x16x32_f16(a, bb, acc[dt], 0, 0, 0);
        }
    }
    int bq = bg / H_, g = bg - bq * H_;
#pragma unroll
    for (int dt = 0; dt < 4; ++dt) {
        int d = dt * 16 + (lane & 15);
#pragma unroll
        for (int r = 0; r < 4; ++r) {
            int row = m0 + (lane >> 4) * 4 + r;
            Oh[((size_t)bq * N_ + row) * C_ + g * HD_ + d] = (f16)acc[dt][r];
        }
    }
}

extern "C" void kernel_launch(void* const* d_in, const int* in_sizes, int n_in,
                              void* d_out, int out_size, void* d_ws, size_t ws_size,
                              hipStream_t stream) {
    const float* x     = (const float*)d_in[0];
    const float* Wqkv  = (const float*)d_in[1];
    const float* Wl    = (const float*)d_in[2];
    const float* bl    = (const float*)d_in[3];
    const float* Ww    = (const float*)d_in[4];
    const float* bw    = (const float*)d_in[5];
    const float* Wproj = (const float*)d_in[6];
    const float* bproj = (const float*)d_in[7];
    float* out = (float*)d_out;

    char* ws = (char*)d_ws;
    size_t off = 0;
    auto alloc = [&](size_t bytes) -> void* {
        void* p = ws + off;
        off += (bytes + 255) & ~(size_t)255;
        return p;
    };
    f16* x_h  = (f16*)alloc((size_t)M_ * C_ * 2);
    f16* wq_h = (f16*)alloc((size_t)C3_ * C_ * 2);
    f16* wp_h = (f16*)alloc((size_t)C_ * C_ * 2);
    f16* q_h  = (f16*)alloc((size_t)B_ * H_ * N_ * HD_ * 2);
    f16* k_h  = (f16*)alloc((size_t)B_ * H_ * N_ * HD_ * 2);
    f16* v_h  = (f16*)alloc((size_t)B_ * H_ * N_ * HD_ * 2);
    f16* vt_h = (f16*)alloc((size_t)B_ * H_ * N_ * HD_ * 2);
    f16* sp   = (f16*)alloc((size_t)B_ * H_ * N_ * N_ * 2);
    float* rmax = (float*)alloc((size_t)B_ * H_ * N_ * 4);
    float* rsum = (float*)alloc((size_t)B_ * H_ * N_ * 4);
    f16* o_h  = (f16*)alloc((size_t)M_ * C_ * 2);

    cvt_f32_f16<<<1024, 256, 0, stream>>>(x,     x_h,  M_ * C_ / 4);
    cvt_f32_f16<<<1024, 256, 0, stream>>>(Wqkv,  wq_h, C3_ * C_ / 4);
    cvt_f32_f16<<<512,  256, 0, stream>>>(Wproj, wp_h, C_ * C_ / 4);

    gemm_qkv<<<dim3(M_ / 128, C3_ / 128), 256, 0, stream>>>(x_h, wq_h, q_h, k_h, v_h);
    transpose_v<<<dim3(N_ / 64, B_ * H_), 256, 0, stream>>>(v_h, vt_h);
    scores_mix<<<dim3(N_ / 32, N_ / 32, B_), 256, 0, stream>>>(q_h, k_h, Wl, bl, sp);
    row_stats<<<B_ * H_ * N_ / 4, 256, 0, stream>>>(sp, rmax, rsum);
    apply_mix<<<dim3(N_, B_), 256, 0, stream>>>(sp, rmax, rsum, Ww, bw);
    pv<<<dim3(N_ / 64, B_ * H_), 256, 0, stream>>>(sp, vt_h, o_h);
    gemm_proj<<<dim3(M_ / 128, C_ / 128), 256, 0, stream>>>(o_h, wp_h, bproj, out);
}